// Round 19
// baseline (249.906 us; speedup 1.0000x reference)
//
#include <hip/hip_runtime.h>
#include <hip/hip_fp16.h>

#define N_NODES 20000
#define FDIM    256
#define NE      400000
#define NK      3
#define LOG2E   1.44269504088896340736f

// Virtual edge stream: [hop0 real E][hop0 self-loops N][hop1 E][hop2 E]
#define TOT_EDGES (3 * NE + N_NODES)
#define NSEG      (3 * N_NODES)             // segments, seg = k*N + dst
#define NCHUNK    ((NSEG + 1023) / 1024)    // 59

typedef __attribute__((ext_vector_type(8))) _Float16 half8;
typedef __attribute__((ext_vector_type(4))) float f32x4;

#define PK(op, d, a, b) \
    asm("v_pk_" op "_f16 %0, %1, %2" : "=v"(d) : "v"(a), "v"(b))
// c += f32(s) * f16(w).sel
#define MIX_FH(c, s, w, sel) \
    asm("v_fma_mix_f32 %0, %1, %2, %0 op_sel:[0," sel ",0] op_sel_hi:[0,1,0]" \
        : "+v"(c) : "v"(s), "v"(w))
#define MIX_HH(p, a, b, sel) \
    asm("v_fma_mix_f32 %0, %1, %2, %0 op_sel:[" sel "," sel ",0] op_sel_hi:[1,1,0]" \
        : "+v"(p) : "v"(a), "v"(b))

// HAZARD LESSONS (rounds 8,10,11,13,15,16):
//  - raw TRANS/DPP adjacent to opaque asm needs manual s_nop wait-states.
//  - multi-output asm blocks need "=&v" early-clobber.
//  - batching 4 edges through monolithic asm blocks (r15/16) REGRESSED;
//    per-edge EXP2_ASM with compiler-scheduled surroundings (r13) is the
//    proven optimum for the edge loop.
#define EXP2_ASM(ee, p) \
    asm("s_nop 1\n\t" \
        "v_exp_f32 %0, %1\n\t" \
        "s_nop 3" \
        : "=v"(ee) : "v"(p))

// ---------------------------------------------------------------------------
// DPP reductions — compiler builtins only (hazard-safe).
// ---------------------------------------------------------------------------
__device__ __forceinline__ float wave_sum(float x)
{
    int v = __float_as_int(x);
    int t;
    t = __builtin_amdgcn_update_dpp(0, v, 0x111, 0xf, 0xf, false);
    v = __float_as_int(__int_as_float(v) + __int_as_float(t));
    t = __builtin_amdgcn_update_dpp(0, v, 0x112, 0xf, 0xf, false);
    v = __float_as_int(__int_as_float(v) + __int_as_float(t));
    t = __builtin_amdgcn_update_dpp(0, v, 0x114, 0xf, 0xf, false);
    v = __float_as_int(__int_as_float(v) + __int_as_float(t));
    t = __builtin_amdgcn_update_dpp(0, v, 0x118, 0xf, 0xf, false);
    v = __float_as_int(__int_as_float(v) + __int_as_float(t));
    t = __builtin_amdgcn_update_dpp(0, v, 0x142, 0xa, 0xf, false);
    v = __float_as_int(__int_as_float(v) + __int_as_float(t));
    t = __builtin_amdgcn_update_dpp(0, v, 0x143, 0xc, 0xf, false);
    v = __float_as_int(__int_as_float(v) + __int_as_float(t));
    return __int_as_float(__builtin_amdgcn_readlane(v, 63));
}

// Sum within each 16-lane row via row_ror butterfly (self-broadcasting).
__device__ __forceinline__ float rowsum16(float x)
{
    int v = __float_as_int(x);
    int t;
    t = __builtin_amdgcn_update_dpp(0, v, 0x121, 0xf, 0xf, false);
    v = __float_as_int(__int_as_float(v) + __int_as_float(t));
    t = __builtin_amdgcn_update_dpp(0, v, 0x122, 0xf, 0xf, false);
    v = __float_as_int(__int_as_float(v) + __int_as_float(t));
    t = __builtin_amdgcn_update_dpp(0, v, 0x124, 0xf, 0xf, false);
    v = __float_as_int(__int_as_float(v) + __int_as_float(t));
    t = __builtin_amdgcn_update_dpp(0, v, 0x128, 0xf, 0xf, false);
    v = __float_as_int(__int_as_float(v) + __int_as_float(t));
    return __int_as_float(v);
}

// ---------------------------------------------------------------------------
// Edge decode
// ---------------------------------------------------------------------------
__device__ __forceinline__ void decode_edge(int i, const int* e0, const int* e1,
                                            const int* e2, int& k, int& src,
                                            int& dst)
{
    if (i < NE) {
        k = 0; src = e0[i]; dst = e0[NE + i];
    } else if (i < NE + N_NODES) {
        k = 0; src = i - NE; dst = src;          // hop-0 self loop
    } else if (i < 2 * NE + N_NODES) {
        int j = i - (NE + N_NODES);
        k = 1; src = e1[j]; dst = e1[NE + j];
    } else {
        int j = i - (2 * NE + N_NODES);
        k = 2; src = e2[j]; dst = e2[NE + j];
    }
}

// ---------------------------------------------------------------------------
// Fused prep: fp16 conversions (x, W^T, att*log2e) + gate softmax (x-conv
// waves are exactly row-aligned) + degree histogram (plain atomicAdd).
// (round-11..13 proven, unchanged)
// ---------------------------------------------------------------------------
#define XCONV_V4 (N_NODES * FDIM / 4)     // 1,280,000 = 5000 blocks exactly
#define WCONV_T  (512 * 64)               // 32,768
#define ATT_N    (3 * 256)
#define CONV_T   (XCONV_V4 + WCONV_T + ATT_N)
#define CONV_B   ((CONV_T + 255) / 256)
#define EDGE_B   ((TOT_EDGES + 255) / 256)

__global__ __launch_bounds__(256) void prep_kernel(
    const float* __restrict__ x, const float* __restrict__ Wl,
    const float* __restrict__ Wr, const float* __restrict__ att,
    const float* __restrict__ Wg, const float* __restrict__ bg,
    const int* __restrict__ e0, const int* __restrict__ e1,
    const int* __restrict__ e2,
    __half* __restrict__ x16, __half* __restrict__ WT16,
    __half* __restrict__ att16, float* __restrict__ gate,
    int* __restrict__ cnt)
{
    if (blockIdx.x < CONV_B) {
        int tid = blockIdx.x * 256 + threadIdx.x;
        if (tid < XCONV_V4) {
            float4 v = ((const float4*)x)[tid];
            ((__half2*)x16)[tid * 2 + 0] = __floats2half2_rn(v.x, v.y);
            ((__half2*)x16)[tid * 2 + 1] = __floats2half2_rn(v.z, v.w);
            // ---- gate: this wave holds the whole row n ----
            const int lane = threadIdx.x & 63;
            const int n    = tid >> 6;
            const int f0   = lane << 2;
            float p0 = 0.f, p1 = 0.f, p2 = 0.f;
            const float* xe = &v.x;
#pragma unroll
            for (int j = 0; j < 4; ++j) {
                float xj = xe[j];
                p0 = fmaf(xj, Wg[(f0 + j) * 3 + 0], p0);
                p1 = fmaf(xj, Wg[(f0 + j) * 3 + 1], p1);
                p2 = fmaf(xj, Wg[(f0 + j) * 3 + 2], p2);
            }
            p0 = wave_sum(p0); p1 = wave_sum(p1); p2 = wave_sum(p2);
            if (lane == 0) {
                float g0 = exp2f((p0 + bg[0]) * LOG2E);
                float g1 = exp2f((p1 + bg[1]) * LOG2E);
                float g2 = exp2f((p2 + bg[2]) * LOG2E);
                float inv = 1.f / (g0 + g1 + g2);
                gate[n * 3 + 0] = g0 * inv;
                gate[n * 3 + 1] = g1 * inv;
                gate[n * 3 + 2] = g2 * inv;
            }
        } else if (tid < XCONV_V4 + WCONV_T) {
            int q  = tid - XCONV_V4;
            int n  = q & 511;             // lane-consecutive -> coalesced reads
            int k4 = (q >> 9) << 2;
            const float* Ws = (n < 256) ? Wl : Wr;
            int nn = n & 255;
            float a = Ws[(k4 + 0) * 256 + nn];
            float b = Ws[(k4 + 1) * 256 + nn];
            float c = Ws[(k4 + 2) * 256 + nn];
            float d = Ws[(k4 + 3) * 256 + nn];
            __half2* dst = (__half2*)(WT16 + (size_t)n * 256 + k4);
            dst[0] = __floats2half2_rn(a, b);
            dst[1] = __floats2half2_rn(c, d);
        } else if (tid < CONV_T) {
            int q = tid - XCONV_V4 - WCONV_T;
            att16[q] = __float2half(att[q] * LOG2E);
        }
    } else {
        int i = (blockIdx.x - CONV_B) * 256 + threadIdx.x;
        if (i < TOT_EDGES) {
            int k, src, dst;
            decode_edge(i, e0, e1, e2, k, src, dst);
            atomicAdd(&cnt[k * N_NODES + dst], 1);
        }
    }
}

// ---------------------------------------------------------------------------
// MFMA fp16 GEMM: [XL16 | XR16][N,256+256] = x16[N,256] @ WT16^T + bias
// (round-5/9/11..13 proven, unchanged)
// ---------------------------------------------------------------------------
__global__ __launch_bounds__(256) void gemm_mfma(
    const __half* __restrict__ x16,   // [N][256]
    const __half* __restrict__ WT16,  // [512][256]  (row n = W column n)
    const float* __restrict__ bl, const float* __restrict__ br,
    __half* __restrict__ XL16, __half* __restrict__ XR16)
{
    __shared__ ushort As[8192];       // 128 rows x 64 halves (128B rows)
    __shared__ ushort Bs[8192];
    char* AsB = (char*)As;
    char* BsB = (char*)Bs;

    const int t    = threadIdx.x;
    const int lane = t & 63;
    const int wid  = t >> 6;
    const int wr   = wid >> 1;
    const int wc   = wid & 1;
    const int row0 = blockIdx.x * 128;
    const int col0 = blockIdx.y * 128;
    const int sr   = t >> 1;

    f32x4 acc[4][4] = {};

    for (int k0 = 0; k0 < FDIM; k0 += 64) {
        {
            const __half* src = x16 + (size_t)(row0 + sr) * 256 + k0 + (t & 1) * 32;
            bool ok = (row0 + sr) < N_NODES;
#pragma unroll
            for (int i = 0; i < 4; ++i) {
                uint4 g = ok ? *(const uint4*)(src + i * 8)
                             : make_uint4(0, 0, 0, 0);
                *(uint4*)(AsB + sr * 128 + (((t & 1) * 4 + i) ^ (sr & 7)) * 16) = g;
            }
        }
        {
            const __half* src = WT16 + (size_t)(col0 + sr) * 256 + k0 + (t & 1) * 32;
#pragma unroll
            for (int i = 0; i < 4; ++i) {
                uint4 g = *(const uint4*)(src + i * 8);
                *(uint4*)(BsB + sr * 128 + (((t & 1) * 4 + i) ^ (sr & 7)) * 16) = g;
            }
        }
        __syncthreads();

#pragma unroll
        for (int ks = 0; ks < 2; ++ks) {
            half8 av[4], bv[4];
#pragma unroll
            for (int mi = 0; mi < 4; ++mi) {
                int arow = wr * 64 + mi * 16 + (lane & 15);
                av[mi] = *(const half8*)(AsB + arow * 128 +
                                         (((ks * 4) + (lane >> 4)) ^ (arow & 7)) * 16);
            }
#pragma unroll
            for (int ni = 0; ni < 4; ++ni) {
                int brow = wc * 64 + ni * 16 + (lane & 15);
                bv[ni] = *(const half8*)(BsB + brow * 128 +
                                         (((ks * 4) + (lane >> 4)) ^ (brow & 7)) * 16);
            }
#pragma unroll
            for (int mi = 0; mi < 4; ++mi)
#pragma unroll
                for (int ni = 0; ni < 4; ++ni)
                    acc[mi][ni] = __builtin_amdgcn_mfma_f32_16x16x32_f16(
                        av[mi], bv[ni], acc[mi][ni], 0, 0, 0);
        }
        __syncthreads();
    }

    const bool left   = (col0 < 256);
    __half* dst       = left ? XL16 : XR16;
    const float* bias = left ? bl : br;
    const int cbase   = left ? col0 : (col0 - 256);

#pragma unroll
    for (int mi = 0; mi < 4; ++mi) {
#pragma unroll
        for (int ni = 0; ni < 4; ++ni) {
            int gc = cbase + wc * 64 + ni * 16 + (lane & 15);
            float bv = bias[gc];
#pragma unroll
            for (int i = 0; i < 4; ++i) {
                int rr = row0 + wr * 64 + mi * 16 + (lane >> 4) * 4 + i;
                if (rr < N_NODES)
                    dst[(size_t)rr * 256 + gc] = __float2half(acc[mi][ni][i] + bv);
            }
        }
    }
}

// ---------------------------------------------------------------------------
// Scan (round-13 proven 2-pass form): pass1 per-chunk sums; pass3 computes
// its own chunk prefix inline (bsum[0..63] zeroed by the memset).
// ---------------------------------------------------------------------------
__global__ __launch_bounds__(1024) void scan_pass1(const int* __restrict__ cnt,
                                                   int* __restrict__ bsum)
{
    int i = blockIdx.x * 1024 + threadIdx.x;
    int v = (i < NSEG) ? cnt[i] : 0;
#pragma unroll
    for (int s = 32; s >= 1; s >>= 1) v += __shfl_xor(v, s);
    if ((threadIdx.x & 63) == 0) atomicAdd(&bsum[blockIdx.x], v);
}

__global__ __launch_bounds__(1024) void scan_pass3(const int* __restrict__ cnt,
                                                   const int* __restrict__ bsum,
                                                   int* __restrict__ goff,
                                                   int* __restrict__ cursor)
{
    __shared__ int wsum[16];
    __shared__ int s_boff;
    const int lane = threadIdx.x & 63;
    const int wid  = threadIdx.x >> 6;
    if (wid == 0) {
        int b = (lane < (int)blockIdx.x && lane < NCHUNK) ? bsum[lane] : 0;
#pragma unroll
        for (int s = 32; s >= 1; s >>= 1) b += __shfl_xor(b, s);
        if (lane == 0) s_boff = b;
    }
    int i  = blockIdx.x * 1024 + threadIdx.x;
    int v0 = (i < NSEG) ? cnt[i] : 0;
    int v  = v0;
#pragma unroll
    for (int s = 1; s < 64; s <<= 1) {
        int t = __shfl_up(v, s);
        if (lane >= s) v += t;
    }
    if (lane == 63) wsum[wid] = v;
    __syncthreads();
    if (wid == 0) {
        int ws = (lane < 16) ? wsum[lane] : 0;
#pragma unroll
        for (int s = 1; s < 16; s <<= 1) {
            int t = __shfl_up(ws, s);
            if (lane >= s) ws += t;
        }
        if (lane < 16) wsum[lane] = ws;
    }
    __syncthreads();
    int excl = s_boff + ((wid > 0) ? wsum[wid - 1] : 0) + (v - v0);
    if (i < NSEG) {
        goff[i]   = excl;
        cursor[i] = excl;
        if (i == NSEG - 1) goff[NSEG] = excl + v0;
    }
}

__global__ void scatter_kernel(const int* __restrict__ e0,
                               const int* __restrict__ e1,
                               const int* __restrict__ e2,
                               int* __restrict__ cursor,
                               int* __restrict__ srcs)
{
    for (int i = blockIdx.x * blockDim.x + threadIdx.x; i < TOT_EDGES;
         i += gridDim.x * blockDim.x) {
        int k, src, dst;
        decode_edge(i, e0, e1, e2, k, src, dst);
        int pos = atomicAdd(&cursor[k * N_NODES + dst], 1);
        srcs[pos] = src;
    }
}

// ---------------------------------------------------------------------------
// ROUND-19: fused aggregation + combine. ONE WAVE PER NODE iterates the 3
// hops internally (round-13 edge loop byte-exact per hop), applies gate and
// bias_out in registers, and writes out[n] directly. Eliminates the msg
// buffer (30 MB of traffic) and the combine dispatch; prologue amortized 3x.
// ---------------------------------------------------------------------------
__global__ __launch_bounds__(256) void hop3_kernel(
    const __half* __restrict__ XL16,    // [N][256]
    const __half* __restrict__ XR16,    // [N][256]
    const int* __restrict__ goff,       // [NSEG+1]
    const int* __restrict__ srcs,       // [TOT_EDGES]
    const __half* __restrict__ att16,   // [3][256]  (LOG2E folded)
    const float* __restrict__ gate,     // [N][3]
    const float* __restrict__ bias_out, // [3][64]
    float* __restrict__ out)            // [N][64]
{
    const int n    = (blockIdx.x * blockDim.x + threadIdx.x) >> 6;
    const int lane = threadIdx.x & 63;
    if (n >= N_NODES) return;
    const int lof = lane << 2;
    const int m4  = (lane & 15) << 2;

    const uint2 xr = *(const uint2*)(XR16 + ((size_t)n << 8) + lof);
    const unsigned K02 = 0x32663266u;    // half2(0.2, 0.2)

    float o0 = 0.f, o1 = 0.f, o2 = 0.f, o3 = 0.f;

#pragma unroll
    for (int k = 0; k < NK; ++k) {
        const uint2 at = *(const uint2*)(att16 + (k << 8) + lof);
        const int jb  = goff[k * N_NODES + n];
        const int je  = goff[k * N_NODES + n + 1];
        const int cnt = je - jb;

        float den = 0.f, c0 = 0.f, c1 = 0.f, c2 = 0.f, c3 = 0.f;

        if (cnt > 0) {
            const int je1 = je - 1;
            int sv = srcs[min(jb + lane, je1)];
            uint2 w0, w1, w2, w3;
            {
                int s_;
                s_ = __builtin_amdgcn_readlane(sv, 0);
                w0 = *(const uint2*)(XL16 + ((size_t)s_ << 8) + lof);
                s_ = __builtin_amdgcn_readlane(sv, min(1, cnt - 1));
                w1 = *(const uint2*)(XL16 + ((size_t)s_ << 8) + lof);
                s_ = __builtin_amdgcn_readlane(sv, min(2, cnt - 1));
                w2 = *(const uint2*)(XL16 + ((size_t)s_ << 8) + lof);
                s_ = __builtin_amdgcn_readlane(sv, min(3, cnt - 1));
                w3 = *(const uint2*)(XL16 + ((size_t)s_ << 8) + lof);
            }

#define EDGE_MATH(W)                                                          \
            {                                                                 \
                unsigned z01, z23, t01, t23, e01, e23;                        \
                PK("add", z01, W.x, xr.x);                                    \
                PK("add", z23, W.y, xr.y);                                    \
                PK("mul", t01, z01, K02);                                     \
                PK("mul", t23, z23, K02);                                     \
                PK("max", e01, z01, t01);                                     \
                PK("max", e23, z23, t23);                                     \
                float p = 0.f;                                                \
                MIX_HH(p, e01, at.x, "0");                                    \
                MIX_HH(p, e01, at.x, "1");                                    \
                MIX_HH(p, e23, at.y, "0");                                    \
                MIX_HH(p, e23, at.y, "1");                                    \
                p = rowsum16(p);                                              \
                float ee;                                                     \
                EXP2_ASM(ee, p);                                              \
                den += ee;                                                    \
                MIX_FH(c0, ee, W.x, "0");                                     \
                MIX_FH(c1, ee, W.x, "1");                                     \
                MIX_FH(c2, ee, W.y, "0");                                     \
                MIX_FH(c3, ee, W.y, "1");                                     \
            }

#define STEP(W, PF) {                                                         \
            EDGE_MATH(W)                                                      \
            if (((PF) & 63) == 0 && (PF) < cnt)                               \
                sv = srcs[min(jb + (PF) + lane, je1)];                        \
            int s_ = __builtin_amdgcn_readlane(sv, (PF) & 63);                \
            W = *(const uint2*)(XL16 + ((size_t)s_ << 8) + lof); }

            const int cnt4 = cnt & ~3;
            for (int u = 0; u < cnt4; u += 4) {
                STEP(w0, u + 4);
                STEP(w1, u + 5);
                STEP(w2, u + 6);
                STEP(w3, u + 7);
            }
            const int rem = cnt - cnt4;
            if (rem > 0) EDGE_MATH(w0)
            if (rem > 1) EDGE_MATH(w1)
            if (rem > 2) EDGE_MATH(w2)
#undef STEP
#undef EDGE_MATH
        }

        const float inv = (cnt > 0) ? (0.25f / den) : 0.f;
        float r0 = c0 * inv, r1 = c1 * inv, r2 = c2 * inv, r3 = c3 * inv;
        // mean over heads: sum the 4 rows
        r0 += __shfl_xor(r0, 16); r0 += __shfl_xor(r0, 32);
        r1 += __shfl_xor(r1, 16); r1 += __shfl_xor(r1, 32);
        r2 += __shfl_xor(r2, 16); r2 += __shfl_xor(r2, 32);
        r3 += __shfl_xor(r3, 16); r3 += __shfl_xor(r3, 32);

        // gate * (msg + bias): accumulate on lanes < 16 (others harmless)
        const float g  = gate[n * 3 + k];
        const float4 b = *(const float4*)(bias_out + (k << 6) + m4);
        o0 = fmaf(g, r0 + b.x, o0);
        o1 = fmaf(g, r1 + b.y, o1);
        o2 = fmaf(g, r2 + b.z, o2);
        o3 = fmaf(g, r3 + b.w, o3);
    }

    if (lane < 16) {
        float4 r = make_float4(o0, o1, o2, o3);
        *(float4*)(out + ((size_t)n << 6) + m4) = r;
    }
}

// ---------------------------------------------------------------------------
extern "C" void kernel_launch(void* const* d_in, const int* in_sizes, int n_in,
                              void* d_out, int out_size, void* d_ws,
                              size_t ws_size, hipStream_t stream)
{
    const float* x        = (const float*)d_in[0];
    const int*   e0       = (const int*)d_in[1];
    const int*   e1       = (const int*)d_in[2];
    const int*   e2       = (const int*)d_in[3];
    const float* Wl       = (const float*)d_in[4];
    const float* bl       = (const float*)d_in[5];
    const float* Wr       = (const float*)d_in[6];
    const float* br       = (const float*)d_in[7];
    const float* att      = (const float*)d_in[8];
    const float* bias_out = (const float*)d_in[9];
    const float* Wg       = (const float*)d_in[10];
    const float* bg       = (const float*)d_in[11];
    float* out = (float*)d_out;

    char* wsb = (char*)d_ws;
    size_t o = 0;
    __half* x16   = (__half*)(wsb + o); o += (size_t)N_NODES * 256 * sizeof(__half);
    __half* WT16  = (__half*)(wsb + o); o += (size_t)512 * 256 * sizeof(__half);
    __half* att16 = (__half*)(wsb + o); o += (size_t)ATT_N * sizeof(__half);
    __half* XL16  = (__half*)(wsb + o); o += (size_t)N_NODES * 256 * sizeof(__half);
    __half* XR16  = (__half*)(wsb + o); o += (size_t)N_NODES * 256 * sizeof(__half);
    int* cnt    = (int*)(wsb + o);   o += (size_t)NSEG * sizeof(int);
    int* bsum   = (int*)(wsb + o);   o += 64 * sizeof(int);
    int* goff   = (int*)(wsb + o);   o += (size_t)(NSEG + 1) * sizeof(int);
    int* cursor = (int*)(wsb + o);   o += (size_t)NSEG * sizeof(int);
    int* srcs   = (int*)(wsb + o);   o += (size_t)TOT_EDGES * sizeof(int);
    float* gate = (float*)(wsb + o); o += (size_t)N_NODES * 3 * sizeof(float);

    // zero cnt + bsum (adjacent)
    hipMemsetAsync(cnt, 0, ((size_t)NSEG + 64) * sizeof(int), stream);

    prep_kernel<<<CONV_B + EDGE_B, 256, 0, stream>>>(
        x, Wl, Wr, att, Wg, bg, e0, e1, e2, x16, WT16, att16, gate, cnt);

    dim3 ggrid((N_NODES + 127) / 128, 4);
    gemm_mfma<<<ggrid, 256, 0, stream>>>(x16, WT16, bl, br, XL16, XR16);

    scan_pass1<<<NCHUNK, 1024, 0, stream>>>(cnt, bsum);
    scan_pass3<<<NCHUNK, 1024, 0, stream>>>(cnt, bsum, goff, cursor);

    int eblocks = (TOT_EDGES + 255) / 256;
    scatter_kernel<<<eblocks, 256, 0, stream>>>(e0, e1, e2, cursor, srcs);

    hop3_kernel<<<(N_NODES * 64 + 255) / 256, 256, 0, stream>>>(
        XL16, XR16, goff, srcs, att16, gate, bias_out, out);
}

// Round 20
// 231.161 us; speedup vs baseline: 1.0811x; 1.0811x over previous
//
#include <hip/hip_runtime.h>
#include <hip/hip_fp16.h>

#define N_NODES 20000
#define FDIM    256
#define NE      400000
#define NK      3
#define LOG2E   1.44269504088896340736f

// Virtual edge stream: [hop0 real E][hop0 self-loops N][hop1 E][hop2 E]
#define TOT_EDGES (3 * NE + N_NODES)
#define NSEG      (3 * N_NODES)             // segments, seg = k*N + dst
#define NCHUNK    ((NSEG + 1023) / 1024)    // 59

typedef __attribute__((ext_vector_type(8))) _Float16 half8;
typedef __attribute__((ext_vector_type(4))) float f32x4;

#define PK(op, d, a, b) \
    asm("v_pk_" op "_f16 %0, %1, %2" : "=v"(d) : "v"(a), "v"(b))
// c += f32(s) * f16(w).sel
#define MIX_FH(c, s, w, sel) \
    asm("v_fma_mix_f32 %0, %1, %2, %0 op_sel:[0," sel ",0] op_sel_hi:[0,1,0]" \
        : "+v"(c) : "v"(s), "v"(w))
#define MIX_HH(p, a, b, sel) \
    asm("v_fma_mix_f32 %0, %1, %2, %0 op_sel:[" sel "," sel ",0] op_sel_hi:[1,1,0]" \
        : "+v"(p) : "v"(a), "v"(b))

// HAZARD LESSONS (rounds 8,10,11,13,15,16):
//  - raw TRANS/DPP adjacent to opaque asm needs manual s_nop wait-states.
//  - multi-output asm blocks need "=&v" early-clobber.
//  - batching edges through monolithic asm blocks (r15/16) REGRESSED;
//    per-edge EXP2_ASM with compiler-scheduled surroundings (r13) is the
//    proven optimum (hop = 85.0 us). Fusing combine into hop (r19) also
//    REGRESSED (VGPR 20->36, occupancy 66->56%). r13 structure is final.
#define EXP2_ASM(ee, p) \
    asm("s_nop 1\n\t" \
        "v_exp_f32 %0, %1\n\t" \
        "s_nop 3" \
        : "=v"(ee) : "v"(p))

// ---------------------------------------------------------------------------
// DPP reductions — compiler builtins only (hazard-safe).
// ---------------------------------------------------------------------------
__device__ __forceinline__ float wave_sum(float x)
{
    int v = __float_as_int(x);
    int t;
    t = __builtin_amdgcn_update_dpp(0, v, 0x111, 0xf, 0xf, false);
    v = __float_as_int(__int_as_float(v) + __int_as_float(t));
    t = __builtin_amdgcn_update_dpp(0, v, 0x112, 0xf, 0xf, false);
    v = __float_as_int(__int_as_float(v) + __int_as_float(t));
    t = __builtin_amdgcn_update_dpp(0, v, 0x114, 0xf, 0xf, false);
    v = __float_as_int(__int_as_float(v) + __int_as_float(t));
    t = __builtin_amdgcn_update_dpp(0, v, 0x118, 0xf, 0xf, false);
    v = __float_as_int(__int_as_float(v) + __int_as_float(t));
    t = __builtin_amdgcn_update_dpp(0, v, 0x142, 0xa, 0xf, false);
    v = __float_as_int(__int_as_float(v) + __int_as_float(t));
    t = __builtin_amdgcn_update_dpp(0, v, 0x143, 0xc, 0xf, false);
    v = __float_as_int(__int_as_float(v) + __int_as_float(t));
    return __int_as_float(__builtin_amdgcn_readlane(v, 63));
}

// Sum within each 16-lane row via row_ror butterfly (self-broadcasting).
__device__ __forceinline__ float rowsum16(float x)
{
    int v = __float_as_int(x);
    int t;
    t = __builtin_amdgcn_update_dpp(0, v, 0x121, 0xf, 0xf, false);
    v = __float_as_int(__int_as_float(v) + __int_as_float(t));
    t = __builtin_amdgcn_update_dpp(0, v, 0x122, 0xf, 0xf, false);
    v = __float_as_int(__int_as_float(v) + __int_as_float(t));
    t = __builtin_amdgcn_update_dpp(0, v, 0x124, 0xf, 0xf, false);
    v = __float_as_int(__int_as_float(v) + __int_as_float(t));
    t = __builtin_amdgcn_update_dpp(0, v, 0x128, 0xf, 0xf, false);
    v = __float_as_int(__int_as_float(v) + __int_as_float(t));
    return __int_as_float(v);
}

// ---------------------------------------------------------------------------
// Edge decode
// ---------------------------------------------------------------------------
__device__ __forceinline__ void decode_edge(int i, const int* e0, const int* e1,
                                            const int* e2, int& k, int& src,
                                            int& dst)
{
    if (i < NE) {
        k = 0; src = e0[i]; dst = e0[NE + i];
    } else if (i < NE + N_NODES) {
        k = 0; src = i - NE; dst = src;          // hop-0 self loop
    } else if (i < 2 * NE + N_NODES) {
        int j = i - (NE + N_NODES);
        k = 1; src = e1[j]; dst = e1[NE + j];
    } else {
        int j = i - (2 * NE + N_NODES);
        k = 2; src = e2[j]; dst = e2[NE + j];
    }
}

// ---------------------------------------------------------------------------
// Fused prep: fp16 conversions (x, W^T, att*log2e) + gate softmax (x-conv
// waves are exactly row-aligned) + degree histogram (plain atomicAdd).
// (round-11..13 proven, unchanged)
// ---------------------------------------------------------------------------
#define XCONV_V4 (N_NODES * FDIM / 4)     // 1,280,000 = 5000 blocks exactly
#define WCONV_T  (512 * 64)               // 32,768
#define ATT_N    (3 * 256)
#define CONV_T   (XCONV_V4 + WCONV_T + ATT_N)
#define CONV_B   ((CONV_T + 255) / 256)
#define EDGE_B   ((TOT_EDGES + 255) / 256)

__global__ __launch_bounds__(256) void prep_kernel(
    const float* __restrict__ x, const float* __restrict__ Wl,
    const float* __restrict__ Wr, const float* __restrict__ att,
    const float* __restrict__ Wg, const float* __restrict__ bg,
    const int* __restrict__ e0, const int* __restrict__ e1,
    const int* __restrict__ e2,
    __half* __restrict__ x16, __half* __restrict__ WT16,
    __half* __restrict__ att16, float* __restrict__ gate,
    int* __restrict__ cnt)
{
    if (blockIdx.x < CONV_B) {
        int tid = blockIdx.x * 256 + threadIdx.x;
        if (tid < XCONV_V4) {
            float4 v = ((const float4*)x)[tid];
            ((__half2*)x16)[tid * 2 + 0] = __floats2half2_rn(v.x, v.y);
            ((__half2*)x16)[tid * 2 + 1] = __floats2half2_rn(v.z, v.w);
            // ---- gate: this wave holds the whole row n ----
            const int lane = threadIdx.x & 63;
            const int n    = tid >> 6;
            const int f0   = lane << 2;
            float p0 = 0.f, p1 = 0.f, p2 = 0.f;
            const float* xe = &v.x;
#pragma unroll
            for (int j = 0; j < 4; ++j) {
                float xj = xe[j];
                p0 = fmaf(xj, Wg[(f0 + j) * 3 + 0], p0);
                p1 = fmaf(xj, Wg[(f0 + j) * 3 + 1], p1);
                p2 = fmaf(xj, Wg[(f0 + j) * 3 + 2], p2);
            }
            p0 = wave_sum(p0); p1 = wave_sum(p1); p2 = wave_sum(p2);
            if (lane == 0) {
                float g0 = exp2f((p0 + bg[0]) * LOG2E);
                float g1 = exp2f((p1 + bg[1]) * LOG2E);
                float g2 = exp2f((p2 + bg[2]) * LOG2E);
                float inv = 1.f / (g0 + g1 + g2);
                gate[n * 3 + 0] = g0 * inv;
                gate[n * 3 + 1] = g1 * inv;
                gate[n * 3 + 2] = g2 * inv;
            }
        } else if (tid < XCONV_V4 + WCONV_T) {
            int q  = tid - XCONV_V4;
            int n  = q & 511;             // lane-consecutive -> coalesced reads
            int k4 = (q >> 9) << 2;
            const float* Ws = (n < 256) ? Wl : Wr;
            int nn = n & 255;
            float a = Ws[(k4 + 0) * 256 + nn];
            float b = Ws[(k4 + 1) * 256 + nn];
            float c = Ws[(k4 + 2) * 256 + nn];
            float d = Ws[(k4 + 3) * 256 + nn];
            __half2* dst = (__half2*)(WT16 + (size_t)n * 256 + k4);
            dst[0] = __floats2half2_rn(a, b);
            dst[1] = __floats2half2_rn(c, d);
        } else if (tid < CONV_T) {
            int q = tid - XCONV_V4 - WCONV_T;
            att16[q] = __float2half(att[q] * LOG2E);
        }
    } else {
        int i = (blockIdx.x - CONV_B) * 256 + threadIdx.x;
        if (i < TOT_EDGES) {
            int k, src, dst;
            decode_edge(i, e0, e1, e2, k, src, dst);
            atomicAdd(&cnt[k * N_NODES + dst], 1);
        }
    }
}

// ---------------------------------------------------------------------------
// MFMA fp16 GEMM + fused scan_pass1 (blockIdx.y == 4 row): both depend only
// on prep and touch disjoint data, so merging into one dispatch is safe.
// GEMM body is the round-5/9/11..13 proven version, unchanged.
// ---------------------------------------------------------------------------
__global__ __launch_bounds__(256) void gemm_scan1(
    const __half* __restrict__ x16,   // [N][256]
    const __half* __restrict__ WT16,  // [512][256]  (row n = W column n)
    const float* __restrict__ bl, const float* __restrict__ br,
    __half* __restrict__ XL16, __half* __restrict__ XR16,
    const int* __restrict__ cnt, int* __restrict__ bsum)
{
    __shared__ ushort As[8192];       // 128 rows x 64 halves (128B rows)
    __shared__ ushort Bs[8192];

    if (blockIdx.y == 4) {            // ---- scan pass 1 (256 thr, 4 el/thr)
        if (blockIdx.x >= NCHUNK) return;
        const int base = blockIdx.x << 10;
        int v = 0;
#pragma unroll
        for (int j = 0; j < 4; ++j) {
            int i = base + (j << 8) + threadIdx.x;
            v += (i < NSEG) ? cnt[i] : 0;
        }
#pragma unroll
        for (int s = 32; s >= 1; s >>= 1) v += __shfl_xor(v, s);
        if ((threadIdx.x & 63) == 0) atomicAdd(&bsum[blockIdx.x], v);
        return;
    }

    char* AsB = (char*)As;
    char* BsB = (char*)Bs;

    const int t    = threadIdx.x;
    const int lane = t & 63;
    const int wid  = t >> 6;
    const int wr   = wid >> 1;
    const int wc   = wid & 1;
    const int row0 = blockIdx.x * 128;
    const int col0 = blockIdx.y * 128;
    const int sr   = t >> 1;

    f32x4 acc[4][4] = {};

    for (int k0 = 0; k0 < FDIM; k0 += 64) {
        {
            const __half* src = x16 + (size_t)(row0 + sr) * 256 + k0 + (t & 1) * 32;
            bool ok = (row0 + sr) < N_NODES;
#pragma unroll
            for (int i = 0; i < 4; ++i) {
                uint4 g = ok ? *(const uint4*)(src + i * 8)
                             : make_uint4(0, 0, 0, 0);
                *(uint4*)(AsB + sr * 128 + (((t & 1) * 4 + i) ^ (sr & 7)) * 16) = g;
            }
        }
        {
            const __half* src = WT16 + (size_t)(col0 + sr) * 256 + k0 + (t & 1) * 32;
#pragma unroll
            for (int i = 0; i < 4; ++i) {
                uint4 g = *(const uint4*)(src + i * 8);
                *(uint4*)(BsB + sr * 128 + (((t & 1) * 4 + i) ^ (sr & 7)) * 16) = g;
            }
        }
        __syncthreads();

#pragma unroll
        for (int ks = 0; ks < 2; ++ks) {
            half8 av[4], bv[4];
#pragma unroll
            for (int mi = 0; mi < 4; ++mi) {
                int arow = wr * 64 + mi * 16 + (lane & 15);
                av[mi] = *(const half8*)(AsB + arow * 128 +
                                         (((ks * 4) + (lane >> 4)) ^ (arow & 7)) * 16);
            }
#pragma unroll
            for (int ni = 0; ni < 4; ++ni) {
                int brow = wc * 64 + ni * 16 + (lane & 15);
                bv[ni] = *(const half8*)(BsB + brow * 128 +
                                         (((ks * 4) + (lane >> 4)) ^ (brow & 7)) * 16);
            }
#pragma unroll
            for (int mi = 0; mi < 4; ++mi)
#pragma unroll
                for (int ni = 0; ni < 4; ++ni)
                    acc[mi][ni] = __builtin_amdgcn_mfma_f32_16x16x32_f16(
                        av[mi], bv[ni], acc[mi][ni], 0, 0, 0);
        }
        __syncthreads();
    }

    const bool left   = (col0 < 256);
    __half* dst       = left ? XL16 : XR16;
    const float* bias = left ? bl : br;
    const int cbase   = left ? col0 : (col0 - 256);

#pragma unroll
    for (int mi = 0; mi < 4; ++mi) {
#pragma unroll
        for (int ni = 0; ni < 4; ++ni) {
            int gc = cbase + wc * 64 + ni * 16 + (lane & 15);
            float bv = bias[gc];
#pragma unroll
            for (int i = 0; i < 4; ++i) {
                int rr = row0 + wr * 64 + mi * 16 + (lane >> 4) * 4 + i;
                if (rr < N_NODES)
                    dst[(size_t)rr * 256 + gc] = __float2half(acc[mi][ni][i] + bv);
            }
        }
    }
}

// ---------------------------------------------------------------------------
// Scan pass 3 (round-13 proven): computes its own chunk prefix inline
// (bsum[0..63] zeroed by the memset).
// ---------------------------------------------------------------------------
__global__ __launch_bounds__(1024) void scan_pass3(const int* __restrict__ cnt,
                                                   const int* __restrict__ bsum,
                                                   int* __restrict__ goff,
                                                   int* __restrict__ cursor)
{
    __shared__ int wsum[16];
    __shared__ int s_boff;
    const int lane = threadIdx.x & 63;
    const int wid  = threadIdx.x >> 6;
    if (wid == 0) {
        int b = (lane < (int)blockIdx.x && lane < NCHUNK) ? bsum[lane] : 0;
#pragma unroll
        for (int s = 32; s >= 1; s >>= 1) b += __shfl_xor(b, s);
        if (lane == 0) s_boff = b;
    }
    int i  = blockIdx.x * 1024 + threadIdx.x;
    int v0 = (i < NSEG) ? cnt[i] : 0;
    int v  = v0;
#pragma unroll
    for (int s = 1; s < 64; s <<= 1) {
        int t = __shfl_up(v, s);
        if (lane >= s) v += t;
    }
    if (lane == 63) wsum[wid] = v;
    __syncthreads();
    if (wid == 0) {
        int ws = (lane < 16) ? wsum[lane] : 0;
#pragma unroll
        for (int s = 1; s < 16; s <<= 1) {
            int t = __shfl_up(ws, s);
            if (lane >= s) ws += t;
        }
        if (lane < 16) wsum[lane] = ws;
    }
    __syncthreads();
    int excl = s_boff + ((wid > 0) ? wsum[wid - 1] : 0) + (v - v0);
    if (i < NSEG) {
        goff[i]   = excl;
        cursor[i] = excl;
        if (i == NSEG - 1) goff[NSEG] = excl + v0;
    }
}

__global__ void scatter_kernel(const int* __restrict__ e0,
                               const int* __restrict__ e1,
                               const int* __restrict__ e2,
                               int* __restrict__ cursor,
                               int* __restrict__ srcs)
{
    for (int i = blockIdx.x * blockDim.x + threadIdx.x; i < TOT_EDGES;
         i += gridDim.x * blockDim.x) {
        int k, src, dst;
        decode_edge(i, e0, e1, e2, k, src, dst);
        int pos = atomicAdd(&cursor[k * N_NODES + dst], 1);
        srcs[pos] = src;
    }
}

// ---------------------------------------------------------------------------
// Per-(node,hop) aggregation: one wave per segment. Packed fp16 edge math,
// fma_mix fp32 accumulation, builtin rowsum16, asm v_exp_f32 (EXP2_ASM),
// bounds-free 4-deep pipeline + uniform tail. (round-13 proven, byte-exact)
// ---------------------------------------------------------------------------
__global__ __launch_bounds__(256) void hop_kernel(
    const __half* __restrict__ XL16,    // [N][256]
    const __half* __restrict__ XR16,    // [N][256]
    const int* __restrict__ goff,       // [NSEG+1]
    const int* __restrict__ srcs,       // [TOT_EDGES]
    const __half* __restrict__ att16,   // [3][256]  (LOG2E folded)
    float* __restrict__ msg)            // [NSEG][64]
{
    const int w    = (blockIdx.x * blockDim.x + threadIdx.x) >> 6;
    const int lane = threadIdx.x & 63;
    if (w >= NSEG) return;
    const int k = w / N_NODES;
    const int n = w - k * N_NODES;
    const int lof = lane << 2;

    const uint2 xr = *(const uint2*)(XR16 + ((size_t)n << 8) + lof);
    const uint2 at = *(const uint2*)(att16 + (k << 8) + lof);
    const unsigned K02 = 0x32663266u;    // half2(0.2, 0.2)

    const int jb  = goff[w];
    const int je  = goff[w + 1];
    const int cnt = je - jb;

    float den = 0.f, c0 = 0.f, c1 = 0.f, c2 = 0.f, c3 = 0.f;

    if (cnt > 0) {
        const int je1 = je - 1;
        int sv = srcs[min(jb + lane, je1)];
        uint2 w0, w1, w2, w3;
        {
            int s_;
            s_ = __builtin_amdgcn_readlane(sv, 0);
            w0 = *(const uint2*)(XL16 + ((size_t)s_ << 8) + lof);
            s_ = __builtin_amdgcn_readlane(sv, min(1, cnt - 1));
            w1 = *(const uint2*)(XL16 + ((size_t)s_ << 8) + lof);
            s_ = __builtin_amdgcn_readlane(sv, min(2, cnt - 1));
            w2 = *(const uint2*)(XL16 + ((size_t)s_ << 8) + lof);
            s_ = __builtin_amdgcn_readlane(sv, min(3, cnt - 1));
            w3 = *(const uint2*)(XL16 + ((size_t)s_ << 8) + lof);
        }

#define EDGE_MATH(W)                                                          \
        {                                                                     \
            unsigned z01, z23, t01, t23, e01, e23;                            \
            PK("add", z01, W.x, xr.x);                                        \
            PK("add", z23, W.y, xr.y);                                        \
            PK("mul", t01, z01, K02);                                         \
            PK("mul", t23, z23, K02);                                         \
            PK("max", e01, z01, t01);                                         \
            PK("max", e23, z23, t23);                                         \
            float p = 0.f;                                                    \
            MIX_HH(p, e01, at.x, "0");                                        \
            MIX_HH(p, e01, at.x, "1");                                        \
            MIX_HH(p, e23, at.y, "0");                                        \
            MIX_HH(p, e23, at.y, "1");                                        \
            p = rowsum16(p);                                                  \
            float ee;                                                         \
            EXP2_ASM(ee, p);                                                  \
            den += ee;                                                        \
            MIX_FH(c0, ee, W.x, "0");                                         \
            MIX_FH(c1, ee, W.x, "1");                                         \
            MIX_FH(c2, ee, W.y, "0");                                         \
            MIX_FH(c3, ee, W.y, "1");                                         \
        }

#define STEP(W, PF) {                                                         \
        EDGE_MATH(W)                                                          \
        if (((PF) & 63) == 0 && (PF) < cnt)                                   \
            sv = srcs[min(jb + (PF) + lane, je1)];                            \
        int s_ = __builtin_amdgcn_readlane(sv, (PF) & 63);                    \
        W = *(const uint2*)(XL16 + ((size_t)s_ << 8) + lof); }

        const int cnt4 = cnt & ~3;
        for (int u = 0; u < cnt4; u += 4) {
            STEP(w0, u + 4);
            STEP(w1, u + 5);
            STEP(w2, u + 6);
            STEP(w3, u + 7);
        }
        const int rem = cnt - cnt4;
        if (rem > 0) EDGE_MATH(w0)
        if (rem > 1) EDGE_MATH(w1)
        if (rem > 2) EDGE_MATH(w2)
#undef STEP
#undef EDGE_MATH
    }

    const float inv = (cnt > 0) ? (0.25f / den) : 0.f;
    float r0 = c0 * inv, r1 = c1 * inv, r2 = c2 * inv, r3 = c3 * inv;
    // mean over heads: sum the 4 rows
    r0 += __shfl_xor(r0, 16); r0 += __shfl_xor(r0, 32);
    r1 += __shfl_xor(r1, 16); r1 += __shfl_xor(r1, 32);
    r2 += __shfl_xor(r2, 16); r2 += __shfl_xor(r2, 32);
    r3 += __shfl_xor(r3, 16); r3 += __shfl_xor(r3, 32);

    if (lane < 16) {
        float4 r = make_float4(r0, r1, r2, r3);
        *(float4*)(msg + ((size_t)w << 6) + (lane << 2)) = r;
    }
}

// ---------------------------------------------------------------------------
// Combine: out[n] = sum_k gate[n][k] * (msg_k[n] + bias_out[k])
// (round-11..13 proven, unchanged)
// ---------------------------------------------------------------------------
__global__ __launch_bounds__(256) void combine_kernel(
    const float* __restrict__ gate, const float* __restrict__ msg,
    const float* __restrict__ bias_out, float* __restrict__ out)
{
    const int n  = blockIdx.x * 16 + (threadIdx.x >> 4);
    const int c4 = (threadIdx.x & 15) << 2;
    if (n >= N_NODES) return;

    float4 o = make_float4(0.f, 0.f, 0.f, 0.f);
#pragma unroll
    for (int k = 0; k < NK; ++k) {
        float g = gate[n * 3 + k];
        float4 m = *(const float4*)(msg +
                     (((size_t)k * N_NODES + n) << 6) + c4);
        float4 b = *(const float4*)(bias_out + (k << 6) + c4);
        o.x = fmaf(g, m.x + b.x, o.x);
        o.y = fmaf(g, m.y + b.y, o.y);
        o.z = fmaf(g, m.z + b.z, o.z);
        o.w = fmaf(g, m.w + b.w, o.w);
    }
    *(float4*)(out + ((size_t)n << 6) + c4) = o;
}

// ---------------------------------------------------------------------------
extern "C" void kernel_launch(void* const* d_in, const int* in_sizes, int n_in,
                              void* d_out, int out_size, void* d_ws,
                              size_t ws_size, hipStream_t stream)
{
    const float* x        = (const float*)d_in[0];
    const int*   e0       = (const int*)d_in[1];
    const int*   e1       = (const int*)d_in[2];
    const int*   e2       = (const int*)d_in[3];
    const float* Wl       = (const float*)d_in[4];
    const float* bl       = (const float*)d_in[5];
    const float* Wr       = (const float*)d_in[6];
    const float* br       = (const float*)d_in[7];
    const float* att      = (const float*)d_in[8];
    const float* bias_out = (const float*)d_in[9];
    const float* Wg       = (const float*)d_in[10];
    const float* bg       = (const float*)d_in[11];
    float* out = (float*)d_out;

    char* wsb = (char*)d_ws;
    size_t o = 0;
    __half* x16   = (__half*)(wsb + o); o += (size_t)N_NODES * 256 * sizeof(__half);
    __half* WT16  = (__half*)(wsb + o); o += (size_t)512 * 256 * sizeof(__half);
    __half* att16 = (__half*)(wsb + o); o += (size_t)ATT_N * sizeof(__half);
    __half* XL16  = (__half*)(wsb + o); o += (size_t)N_NODES * 256 * sizeof(__half);
    __half* XR16  = (__half*)(wsb + o); o += (size_t)N_NODES * 256 * sizeof(__half);
    float*  msg   = (float*)(wsb + o);  o += (size_t)NSEG * 64 * sizeof(float);
    int* cnt    = (int*)(wsb + o);   o += (size_t)NSEG * sizeof(int);
    int* bsum   = (int*)(wsb + o);   o += 64 * sizeof(int);
    int* goff   = (int*)(wsb + o);   o += (size_t)(NSEG + 1) * sizeof(int);
    int* cursor = (int*)(wsb + o);   o += (size_t)NSEG * sizeof(int);
    int* srcs   = (int*)(wsb + o);   o += (size_t)TOT_EDGES * sizeof(int);
    float* gate = (float*)(wsb + o); o += (size_t)N_NODES * 3 * sizeof(float);

    // zero cnt + bsum (adjacent)
    hipMemsetAsync(cnt, 0, ((size_t)NSEG + 64) * sizeof(int), stream);

    prep_kernel<<<CONV_B + EDGE_B, 256, 0, stream>>>(
        x, Wl, Wr, att, Wg, bg, e0, e1, e2, x16, WT16, att16, gate, cnt);

    dim3 ggrid((N_NODES + 127) / 128, 5);   // y<4: gemm tiles, y==4: scan1
    gemm_scan1<<<ggrid, 256, 0, stream>>>(x16, WT16, bl, br, XL16, XR16,
                                          cnt, bsum);

    scan_pass3<<<NCHUNK, 1024, 0, stream>>>(cnt, bsum, goff, cursor);

    int eblocks = (TOT_EDGES + 255) / 256;
    scatter_kernel<<<eblocks, 256, 0, stream>>>(e0, e1, e2, cursor, srcs);

    hop_kernel<<<(NSEG * 64 + 255) / 256, 256, 0, stream>>>(
        XL16, XR16, goff, srcs, att16, msg);

    combine_kernel<<<(N_NODES + 15) / 16, 256, 0, stream>>>(
        gate, msg, bias_out, out);
}